// Round 2
// baseline (340.937 us; speedup 1.0000x reference)
//
#include <hip/hip_runtime.h>
#include <math.h>

static constexpr int B_ = 8, C_ = 512, T_ = 2048, C3_ = 1536;
static constexpr float INV_TEMP = 1.0f / 0.07f;

typedef __attribute__((ext_vector_type(8))) short short8;
typedef __attribute__((ext_vector_type(4))) float floatx4;

__device__ __forceinline__ float b2f(unsigned short u) {
  union { unsigned int i; float f; } v; v.i = ((unsigned int)u) << 16; return v.f;
}
__device__ __forceinline__ unsigned short f2b(float f) {
  union { float f; unsigned int i; } v; v.f = f;
  const unsigned int x = v.i;
  return (unsigned short)((x + 0x7FFFu + ((x >> 16) & 1u)) >> 16);
}
__device__ __forceinline__ void gld16(const unsigned short* g, unsigned short* l) {
  __builtin_amdgcn_global_load_lds(
      (const __attribute__((address_space(1))) void*)g,
      (__attribute__((address_space(3))) void*)l, 16, 0, 0);
}

#define FENCE  asm volatile("" ::: "memory")
#define BAR()  do { FENCE; __builtin_amdgcn_s_barrier(); FENCE; } while (0)
#define LGKM0  asm volatile("s_waitcnt lgkmcnt(0)" ::: "memory")
#define VMC4   asm volatile("s_waitcnt vmcnt(4)" ::: "memory")
#define VMC0   asm volatile("s_waitcnt vmcnt(0)" ::: "memory")

// ---------------------------------------------------------------------------
// TN-form bf16 MFMA GEMM, 256x256 tile, BK=64, 512 thr = 8 waves (2Mx4N, each
// wave 128x64 out). 8-phase schedule per iteration (2 K-tiles / iter), counted
// s_waitcnt vmcnt(4) only at phases 4/8 so global_load_lds stays in flight
// across barriers. LDS: 2 buffers x (A 256x64 + B 256x64) bf16 = 128 KiB.
// Swizzle: 16B k-granule ^= (row&7) on ds_read; staging writes LDS linearly
// with the INVERSE swizzle applied to the per-lane GLOBAL source address.
//
// Phase compute order per K-tile (quadrants of the wave's 128x64, BK=64):
//   p1:(ihi0,jh0) p2:(ihi0,jh1) p3:(ihi1,jh0) p4:(ihi1,jh1)
// Stage schedule (1 half-tile = 16KiB = 2 gld16/thread per phase):
//   p1: buf1.A-top(kt+1)  p2: buf1.A-bot(kt+1)
//   p3: buf0.B-top(kt+2)  p4: buf0.B-bot(kt+2) + vmcnt(4)
//   p5: buf0.A-top(kt+2)  p6: buf0.A-bot(kt+2)
//   p7: buf1.B-top(kt+3)  p8: buf1.B-bot(kt+3) + vmcnt(4)
// Each vmcnt(4) leaves exactly the last 2 stage calls in flight and drains the
// 4 half-tiles the upcoming K-tile needs; each stage dest slot was last read
// >=1 barrier pair earlier.
//
// MODE 0: plain store.  MODE 2: softmax epilogue (fixed-max exp, bf16 store,
// denom atomics of ROUNDED weights).  MODE 3: row divide by rs.
// ---------------------------------------------------------------------------
template<bool OUT_BF16, int MODE>
__global__ __launch_bounds__(512, 2)
void gemm256(const unsigned short* __restrict__ A, const unsigned short* __restrict__ B,
             void* __restrict__ Cout, int K, int lda, int ldb, int ldc,
             long long sA, long long sB, long long sC,
             const float* __restrict__ rs, const float* __restrict__ cs,
             float* __restrict__ denom, int rcStride, float scale)
{
  extern __shared__ unsigned short S[];   // [2][A:16384 | B:16384] shorts

  const int bz = blockIdx.z;
  A += (long long)bz * sA;
  B += (long long)bz * sB;
  if (MODE == 2) { rs += (long long)bz * rcStride; cs += (long long)bz * rcStride;
                   denom += (long long)bz * rcStride; }
  if (MODE == 3) { rs += (long long)bz * rcStride; }
  const int m0 = blockIdx.y * 256, n0 = blockIdx.x * 256;
  const int tid = threadIdx.x;
  const int w = tid >> 6, lane = tid & 63;
  const int rl = lane & 15, qd = lane >> 4;
  const int wm = (w >> 2) * 128, wn = (w & 3) * 64;

  // staging: lane -> (8-row chunk row lr, granule slot lane&7); the GLOBAL
  // source granule is pre-swizzled so LDS slot (r, gs) holds granule gs^(r&7).
  const int lr = lane >> 3;                  // 0..7
  const int lg = ((lane & 7) ^ lr) * 8;      // swizzled source granule (elems)
  const unsigned short* gA = A + (long long)(m0 + w * 8 + lr) * lda + lg;
  const unsigned short* gB = B + (long long)(n0 + w * 8 + lr) * ldb + lg;

  // fragment read offsets (swizzle applied on read; row&7 == rl&7 always)
  const int g0 = (qd ^ (rl & 7)) * 8;        // k-step 0 granule
  const int g1 = ((4 + qd) ^ (rl & 7)) * 8;  // k-step 1 granule
  const int aBase = (wm + rl) * 64, bBase = (wn + rl) * 64;

  floatx4 acc[8][4];
  #pragma unroll
  for (int i = 0; i < 8; ++i)
    #pragma unroll
    for (int j = 0; j < 4; ++j) acc[i][j] = 0.0f;

  auto stA = [&](int buf, int h, int kt) {
    unsigned short* d = S + buf * 32768 + h * 8192 + w * 512;
    const unsigned short* s = gA + (long long)(h * 128) * lda + kt * 64;
    gld16(s, d);
    gld16(s + (long long)64 * lda, d + 4096);
  };
  auto stB = [&](int buf, int h, int kt) {
    unsigned short* d = S + buf * 32768 + 16384 + h * 8192 + w * 512;
    const unsigned short* s = gB + (long long)(h * 128) * ldb + kt * 64;
    gld16(s, d);
    gld16(s + (long long)64 * ldb, d + 4096);
  };

  short8 fa[4][2], fl[2][2], fr[2][2];
  auto rdA = [&](int buf, int ih) {
    const unsigned short* p = S + buf * 32768 + aBase + ih * 4096;
    #pragma unroll
    for (int i = 0; i < 4; ++i) {
      fa[i][0] = *(const short8*)(p + i * 1024 + g0);
      fa[i][1] = *(const short8*)(p + i * 1024 + g1);
    }
  };
  auto rdB = [&](short8 (&fb)[2][2], int buf, int jh) {
    const unsigned short* p = S + buf * 32768 + 16384 + bBase + jh * 2048;
    #pragma unroll
    for (int j = 0; j < 2; ++j) {
      fb[j][0] = *(const short8*)(p + j * 1024 + g0);
      fb[j][1] = *(const short8*)(p + j * 1024 + g1);
    }
  };
  auto mm = [&](short8 (&fb)[2][2], int ih, int jh) {
    #pragma unroll
    for (int i = 0; i < 4; ++i)
      #pragma unroll
      for (int j = 0; j < 2; ++j) {
        floatx4& a = acc[ih * 4 + i][jh * 2 + j];
        a = __builtin_amdgcn_mfma_f32_16x16x32_bf16(fa[i][0], fb[j][0], a, 0, 0, 0);
        a = __builtin_amdgcn_mfma_f32_16x16x32_bf16(fa[i][1], fb[j][1], a, 0, 0, 0);
      }
  };

  auto iter = [&](int kt, bool st2, bool st3, bool tail) {
    // ph1
    rdA(0, 0); rdB(fl, 0, 0);
    stA(1, 0, kt + 1);
    BAR(); LGKM0;
    __builtin_amdgcn_s_setprio(1); mm(fl, 0, 0); __builtin_amdgcn_s_setprio(0);
    BAR();
    // ph2
    rdB(fr, 0, 1);
    stA(1, 1, kt + 1);
    BAR(); LGKM0;
    __builtin_amdgcn_s_setprio(1); mm(fr, 0, 1); __builtin_amdgcn_s_setprio(0);
    BAR();
    // ph3
    rdA(0, 1);
    if (st2) stB(0, 0, kt + 2);
    BAR(); LGKM0;
    __builtin_amdgcn_s_setprio(1); mm(fl, 1, 0); __builtin_amdgcn_s_setprio(0);
    BAR();
    // ph4
    if (st2) stB(0, 1, kt + 2);
    if (tail) { VMC0; } else { VMC4; }
    BAR();
    __builtin_amdgcn_s_setprio(1); mm(fr, 1, 1); __builtin_amdgcn_s_setprio(0);
    BAR();
    // ph5
    rdA(1, 0); rdB(fl, 1, 0);
    if (st2) stA(0, 0, kt + 2);
    BAR(); LGKM0;
    __builtin_amdgcn_s_setprio(1); mm(fl, 0, 0); __builtin_amdgcn_s_setprio(0);
    BAR();
    // ph6
    rdB(fr, 1, 1);
    if (st2) stA(0, 1, kt + 2);
    BAR(); LGKM0;
    __builtin_amdgcn_s_setprio(1); mm(fr, 0, 1); __builtin_amdgcn_s_setprio(0);
    BAR();
    // ph7
    rdA(1, 1);
    if (st3) stB(1, 0, kt + 3);
    BAR(); LGKM0;
    __builtin_amdgcn_s_setprio(1); mm(fl, 1, 0); __builtin_amdgcn_s_setprio(0);
    BAR();
    // ph8
    if (st3) stB(1, 1, kt + 3);
    if (!tail) { VMC4; }
    BAR();
    __builtin_amdgcn_s_setprio(1); mm(fr, 1, 1); __builtin_amdgcn_s_setprio(0);
    BAR();
  };

  const int niter = K >> 7;   // K / 128; 2 K-tiles per iteration
  // prologue: buf0 = K-tile 0 complete; buf1.B halves of K-tile 1 in flight
  stB(0, 0, 0); stB(0, 1, 0); stA(0, 0, 0); stA(0, 1, 0);
  stB(1, 0, 1); stB(1, 1, 1);
  VMC4; BAR();
  for (int i = 0; i < niter - 1; ++i) iter(2 * i, true, true, false);
  iter(2 * (niter - 1), false, false, true);

  // epilogue: C/D layout col=lane&15, row=(lane>>4)*4+reg
  float cf4[4];
  if (MODE == 2) {
    #pragma unroll
    for (int j = 0; j < 4; ++j) cf4[j] = cs[n0 + wn + j * 16 + rl];
  }
  #pragma unroll
  for (int i = 0; i < 8; ++i) {
    #pragma unroll
    for (int r = 0; r < 4; ++r) {
      const int row = m0 + wm + i * 16 + qd * 4 + r;
      float rowf = 0.f;
      if (MODE == 2) rowf = rs[row] * scale;
      if (MODE == 3) rowf = 1.0f / rs[row];
      float rsum = 0.f;
      #pragma unroll
      for (int j = 0; j < 4; ++j) {
        const int col = n0 + wn + j * 16 + rl;
        float v = acc[i][j][r];
        if (MODE == 2) {
          const float s = v * rowf * cf4[j];
          const unsigned short pb = f2b(__expf(s - scale));
          rsum += b2f(pb);   // sum the ROUNDED weights
          ((unsigned short*)Cout)[(long long)bz * sC + (long long)row * ldc + col] = pb;
          continue;
        }
        if (MODE == 3) v *= rowf;
        const long long idx = (long long)bz * sC + (long long)row * ldc + col;
        if (OUT_BF16) ((unsigned short*)Cout)[idx] = f2b(v);
        else          ((float*)Cout)[idx] = v;
      }
      if (MODE == 2) {
        #pragma unroll
        for (int m = 1; m < 16; m <<= 1) rsum += __shfl_xor(rsum, m);
        if (rl == 0) atomicAdd(denom + row, rsum);
      }
    }
  }
}

__global__ __launch_bounds__(256)
void zero_f(float* __restrict__ p, int n)
{
  const int i = blockIdx.x * 256 + threadIdx.x;
  if (i < n) p[i] = 0.f;
}

// ---------------------------------------------------------------------------
// x [B,C,T] fp32 -> xT [B,T,C] bf16 (transpose-convert, 32x32 LDS tiles)
// ---------------------------------------------------------------------------
__global__ __launch_bounds__(256)
void conv_xT(const float* __restrict__ x, unsigned short* __restrict__ xT)
{
  const int b = blockIdx.z, t0 = blockIdx.x * 32, c0 = blockIdx.y * 32;
  const int tx = threadIdx.x & 31, ty = threadIdx.x >> 5;
  __shared__ float tile[32][33];
  const float* src = x + (long long)b * C_ * T_;
  #pragma unroll
  for (int r = 0; r < 4; ++r)
    tile[ty + 8 * r][tx] = src[(long long)(c0 + ty + 8 * r) * T_ + t0 + tx];
  __syncthreads();
  unsigned short* dst = xT + (long long)b * T_ * C_;
  #pragma unroll
  for (int r = 0; r < 4; ++r)
    dst[(long long)(t0 + ty + 8 * r) * C_ + c0 + tx] = f2b(tile[tx][ty + 8 * r]);
}

__global__ __launch_bounds__(256)
void conv_bf(const float* __restrict__ in, unsigned short* __restrict__ out, int n)
{
  const int i = blockIdx.x * 256 + threadIdx.x;
  if (i < n) out[i] = f2b(in[i]);
}

// ---------------------------------------------------------------------------
// Depthwise-3 (zero pad) on v channels [2C,3C): bf16 in [B,3C,T] -> v [B,C,T]
// ---------------------------------------------------------------------------
__global__ __launch_bounds__(256)
void dw_v(const unsigned short* __restrict__ qkv, const float* __restrict__ wdw,
          unsigned short* __restrict__ vout)
{
  const long long idx = (long long)blockIdx.x * 256 + threadIdx.x;  // [B*C*T)
  const int t = (int)(idx % T_);
  const long long rem = idx / T_;
  const int c = (int)(rem % C_), b = (int)(rem / C_);
  const unsigned short* src = qkv + ((long long)(b * C3_ + 2 * C_ + c)) * T_;
  const float* wp = wdw + (2 * C_ + c) * 3;
  const float xm = (t > 0)      ? b2f(src[t - 1]) : 0.f;
  const float x0 = b2f(src[t]);
  const float xp = (t < T_ - 1) ? b2f(src[t + 1]) : 0.f;
  vout[(long long)(b * C_ + c) * T_ + t] = f2b(fmaf(wp[0], xm, fmaf(wp[1], x0, wp[2] * xp)));
}

// ---------------------------------------------------------------------------
// Depthwise-3 + transpose for q (p=0) / k (p=1): [B,3C,T] -> [B,T,C] bf16
// ---------------------------------------------------------------------------
__global__ __launch_bounds__(256)
void dw_qk_t(const unsigned short* __restrict__ qkv, const float* __restrict__ wdw,
             unsigned short* __restrict__ qT, unsigned short* __restrict__ kT)
{
  const int bz = blockIdx.z, b = bz >> 1, p = bz & 1;
  const int t0 = blockIdx.x * 32, c0 = blockIdx.y * 32;
  const int tx = threadIdx.x & 31, ty = threadIdx.x >> 5;
  __shared__ float tin[32][34];   // [c][t-1 .. t+32]
  __shared__ float tout[32][33];  // [t][c]
  const int chb = b * C3_ + p * C_;
  #pragma unroll
  for (int r = 0; r < 4; ++r) {
    const int cy = ty + 8 * r;
    const unsigned short* src = qkv + (long long)(chb + c0 + cy) * T_;
    int t = t0 - 1 + tx;
    tin[cy][tx] = (t >= 0 && t < T_) ? b2f(src[t]) : 0.f;
    if (tx < 2) {
      const int t2 = t0 + 31 + tx;
      tin[cy][32 + tx] = (t2 < T_) ? b2f(src[t2]) : 0.f;
    }
  }
  __syncthreads();
  #pragma unroll
  for (int r = 0; r < 4; ++r) {
    const int cy = ty + 8 * r;
    const float* wp = wdw + (long long)(p * C_ + c0 + cy) * 3;
    tout[tx][cy] = fmaf(wp[0], tin[cy][tx], fmaf(wp[1], tin[cy][tx + 1], wp[2] * tin[cy][tx + 2]));
  }
  __syncthreads();
  unsigned short* dst = (p == 0 ? qT : kT) + (long long)b * T_ * C_;
  #pragma unroll
  for (int r = 0; r < 4; ++r)
    dst[(long long)(t0 + ty + 8 * r) * C_ + c0 + tx] = f2b(tout[ty + 8 * r][tx]);
}

// ---------------------------------------------------------------------------
// Row L2-norm stats from bf16 [B*T, C] rows: inv = 1/max(||row||,eps)
// ---------------------------------------------------------------------------
__global__ __launch_bounds__(256)
void norms_k(const unsigned short* __restrict__ qT, const unsigned short* __restrict__ kT,
             float* __restrict__ inv_nq, float* __restrict__ inv_nk)
{
  const int wave = threadIdx.x >> 6, lane = threadIdx.x & 63;
  const long long row = (long long)blockIdx.x * 4 + wave;
  const unsigned short* src = (blockIdx.y == 0 ? qT : kT) + row * C_ + lane * 8;
  const uint4 u = *(const uint4*)src;
  float ss = 0.f;
  const unsigned int uu[4] = {u.x, u.y, u.z, u.w};
  #pragma unroll
  for (int i = 0; i < 4; ++i) {
    const float lo = b2f(uu[i] & 0xFFFF), hi = b2f(uu[i] >> 16);
    ss = fmaf(lo, lo, ss); ss = fmaf(hi, hi, ss);
  }
  #pragma unroll
  for (int m = 32; m; m >>= 1) ss += __shfl_xor(ss, m);
  if (lane == 0)
    (blockIdx.y == 0 ? inv_nq : inv_nk)[row] = 1.f / fmaxf(sqrtf(ss), 1e-12f);
}

// ---------------------------------------------------------------------------
// Workspace arena (bytes), ~185.3 MB:
//  [0, 64M)    early: xT (16M) + wqkv_bf; late: av_t [B,T,C] bf16 (16M)
//  [64M,80M) qT  [80M,96M) kT  [96M,112M) vb
//  [112M,176M) attn bf16 [B,T,T] — early alias: qkv_bf (48M, dead after dw)
//  [176M,...)  wproj_bf, inv_nq, inv_nk, denom
// ---------------------------------------------------------------------------
extern "C" void kernel_launch(void* const* d_in, const int* in_sizes, int n_in,
                              void* d_out, int out_size, void* d_ws, size_t ws_size,
                              hipStream_t stream)
{
  const float* x      = (const float*)d_in[0];
  const float* w_qkv  = (const float*)d_in[1];
  const float* w_dw   = (const float*)d_in[2];
  const float* w_proj = (const float*)d_in[3];
  float* out = (float*)d_out;

  static int attr_done = 0;
  if (!attr_done) {
    hipFuncSetAttribute((const void*)&gemm256<true, 0>,
                        hipFuncAttributeMaxDynamicSharedMemorySize, 131072);
    hipFuncSetAttribute((const void*)&gemm256<true, 2>,
                        hipFuncAttributeMaxDynamicSharedMemorySize, 131072);
    hipFuncSetAttribute((const void*)&gemm256<true, 3>,
                        hipFuncAttributeMaxDynamicSharedMemorySize, 131072);
    hipFuncSetAttribute((const void*)&gemm256<false, 0>,
                        hipFuncAttributeMaxDynamicSharedMemorySize, 131072);
    attr_done = 1;
  }

  char* base = (char*)d_ws;
  unsigned short* xT      = (unsigned short*)base;                    // early
  unsigned short* wqkv_bf = (unsigned short*)(base + 16777216);       // early
  unsigned short* av_t    = (unsigned short*)base;                    // late
  char* p = base + 67108864;
  unsigned short* qT = (unsigned short*)p; p += 16777216;
  unsigned short* kT = (unsigned short*)p; p += 16777216;
  unsigned short* vb = (unsigned short*)p; p += 16777216;
  unsigned short* attn   = (unsigned short*)p;
  unsigned short* qkv_bf = (unsigned short*)p;                        // early alias
  p += 67108864;
  unsigned short* wproj_bf = (unsigned short*)p; p += 524288;
  float* inv_nq = (float*)p; p += 65536;
  float* inv_nk = (float*)p; p += 65536;
  float* denom  = (float*)p;

  const long long TC = (long long)T_ * C_, TT = (long long)T_ * T_;

  // 0) conversions + denom zero
  conv_xT<<<dim3(T_ / 32, C_ / 32, B_), 256, 0, stream>>>(x, xT);
  conv_bf<<<(C3_ * C_) / 256, 256, 0, stream>>>(w_qkv, wqkv_bf, C3_ * C_);
  conv_bf<<<(C_ * C_) / 256, 256, 0, stream>>>(w_proj, wproj_bf, C_ * C_);
  zero_f<<<(B_ * T_) / 256, 256, 0, stream>>>(denom, B_ * T_);

  // 1) qkv[b][o][t] = sum_c wqkv[o][c] * x[c][t]   (M=1536, N=2048, K=512)
  gemm256<true, 0><<<dim3(8, 6, B_), 512, 131072, stream>>>(
      wqkv_bf, xT, qkv_bf, C_, C_, C_, T_,
      0LL, TC, (long long)C3_ * T_, nullptr, nullptr, nullptr, 0, 1.f);

  // 2) depthwise conv
  dw_v<<<(int)(((long long)B_ * C_ * T_) / 256), 256, 0, stream>>>(qkv_bf, w_dw, vb);
  dw_qk_t<<<dim3(T_ / 32, C_ / 32, B_ * 2), 256, 0, stream>>>(qkv_bf, w_dw, qT, kT);

  // 3) channel-L2 stats (from bf16 values)
  norms_k<<<dim3((B_ * T_) / 4, 2), 256, 0, stream>>>(qT, kT, inv_nq, inv_nk);

  // 4) scores + fused softmax (fixed-max exp) -> attn bf16 + denom atomics
  //    (M=N=2048, K=512)
  gemm256<true, 2><<<dim3(8, 8, B_), 512, 131072, stream>>>(
      qT, kT, attn, C_, C_, C_, T_,
      TC, TC, TT, inv_nq, inv_nk, denom, T_, INV_TEMP);

  // 5) av_t[b][t][c] = (sum_s attn[t][s] * v[c][s]) / denom[t]
  //    (M=2048, N=512, K=2048)
  gemm256<true, 3><<<dim3(2, 8, B_), 512, 131072, stream>>>(
      attn, vb, av_t, T_, T_, T_, C_,
      TT, (long long)C_ * T_, TC, denom, nullptr, nullptr, T_, 1.f);

  // 6) out[b][o][t] = sum_c wproj[o][c] * av_t[t][c]   (M=512, N=2048, K=512)
  gemm256<false, 0><<<dim3(8, 2, B_), 512, 131072, stream>>>(
      wproj_bf, av_t, out, C_, C_, C_, T_,
      0LL, TC, (long long)C_ * T_, nullptr, nullptr, nullptr, 0, 1.f);
}

// Round 3
// 330.344 us; speedup vs baseline: 1.0321x; 1.0321x over previous
//
#include <hip/hip_runtime.h>
#include <math.h>

static constexpr int B_ = 8, C_ = 512, T_ = 2048, C3_ = 1536;
static constexpr float INV_TEMP = 1.0f / 0.07f;

typedef __attribute__((ext_vector_type(8))) short short8;
typedef __attribute__((ext_vector_type(4))) float floatx4;

__device__ __forceinline__ float b2f(unsigned short u) {
  union { unsigned int i; float f; } v; v.i = ((unsigned int)u) << 16; return v.f;
}
__device__ __forceinline__ unsigned short f2b(float f) {
  union { float f; unsigned int i; } v; v.f = f;
  const unsigned int x = v.i;
  return (unsigned short)((x + 0x7FFFu + ((x >> 16) & 1u)) >> 16);
}
__device__ __forceinline__ void gld16(const unsigned short* g, unsigned short* l) {
  __builtin_amdgcn_global_load_lds(
      (const __attribute__((address_space(1))) void*)g,
      (__attribute__((address_space(3))) void*)l, 16, 0, 0);
}

#define FENCE  asm volatile("" ::: "memory")
#define BAR()  do { FENCE; __builtin_amdgcn_s_barrier(); FENCE; } while (0)
#define LGKM0  asm volatile("s_waitcnt lgkmcnt(0)" ::: "memory")
#define VMC6   asm volatile("s_waitcnt vmcnt(6)" ::: "memory")
#define VMC4   asm volatile("s_waitcnt vmcnt(4)" ::: "memory")
#define VMC0   asm volatile("s_waitcnt vmcnt(0)" ::: "memory")
#define SCHED0 __builtin_amdgcn_sched_barrier(0)

// ---------------------------------------------------------------------------
// gemm_tn: proven 128x128/BK=32 TN bf16 GEMM (3-deep LDS ring, counted
// vmcnt(4) at the barrier). Used for qkv / AV / proj where grid fit matters
// more than per-block pipeline depth.
// MODE 0: plain store. MODE 2: softmax epilogue. MODE 3: row divide.
// ---------------------------------------------------------------------------
template<bool OUT_BF16, int MODE>
__global__ __launch_bounds__(256)
void gemm_tn(const unsigned short* __restrict__ A, const unsigned short* __restrict__ B,
             void* __restrict__ Cout, int K, int lda, int ldb, int ldc,
             long long sA, long long sB, long long sC,
             const float* __restrict__ rs, const float* __restrict__ cs,
             float* __restrict__ denom, int rcStride, float scale)
{
  constexpr int NL = 4;   // gld16 per wave per tile

  const int bz = blockIdx.z;
  A += (long long)bz * sA;
  B += (long long)bz * sB;
  if (MODE == 2) { rs += (long long)bz * rcStride; cs += (long long)bz * rcStride;
                   denom += (long long)bz * rcStride; }
  if (MODE == 3) { rs += (long long)bz * rcStride; }
  const int m0 = blockIdx.y * 128, n0 = blockIdx.x * 128;
  const int tid = threadIdx.x;
  const int w = tid >> 6, lane = tid & 63;
  const int wm = (w >> 1) * 64, wn = (w & 1) * 64;
  const int rl = lane & 15, qd = lane >> 4;

  __shared__ __align__(16) unsigned short As[3][128 * 32];
  __shared__ __align__(16) unsigned short Bs[3][128 * 32];

  const int sr = lane >> 2, sg = lane & 3;
  const int ml0 = 32 * w + sr, ml1 = ml0 + 16;
  const int q0 = sg ^ ((ml0 >> 1) & 3), q1 = sg ^ ((ml1 >> 1) & 3);
  const unsigned short* gA0 = A + (long long)(m0 + ml0) * lda + q0 * 8;
  const unsigned short* gA1 = A + (long long)(m0 + ml1) * lda + q1 * 8;
  const unsigned short* gB0 = B + (long long)(n0 + ml0) * ldb + q0 * 8;
  const unsigned short* gB1 = B + (long long)(n0 + ml1) * ldb + q1 * 8;

  int aoff[4], boff[4];
  #pragma unroll
  for (int i = 0; i < 4; ++i) {
    const int mr = wm + i * 16 + rl;
    aoff[i] = mr * 32 + ((qd ^ ((mr >> 1) & 3)) * 8);
    const int nr = wn + i * 16 + rl;
    boff[i] = nr * 32 + ((qd ^ ((nr >> 1) & 3)) * 8);
  }

  floatx4 acc[4][4];
  #pragma unroll
  for (int i = 0; i < 4; ++i)
    #pragma unroll
    for (int j = 0; j < 4; ++j) acc[i][j] = 0.0f;

  auto stage = [&](int t, int bf) {
    const int ko = t * 32;
    gld16(gA0 + ko, As[bf] + (32 * w) * 32);
    gld16(gA1 + ko, As[bf] + (32 * w + 16) * 32);
    gld16(gB0 + ko, Bs[bf] + (32 * w) * 32);
    gld16(gB1 + ko, Bs[bf] + (32 * w + 16) * 32);
  };
  auto compute = [&](int bf) {
    short8 fa[4], fb[4];
    #pragma unroll
    for (int i = 0; i < 4; ++i) fa[i] = *(const short8*)(As[bf] + aoff[i]);
    #pragma unroll
    for (int j = 0; j < 4; ++j) fb[j] = *(const short8*)(Bs[bf] + boff[j]);
    #pragma unroll
    for (int i = 0; i < 4; ++i)
      #pragma unroll
      for (int j = 0; j < 4; ++j)
        acc[i][j] = __builtin_amdgcn_mfma_f32_16x16x32_bf16(fa[i], fb[j], acc[i][j], 0, 0, 0);
  };

  const int niter = K >> 5;
  stage(0, 0);
  stage(1, 1);
  int buf = 0;
  for (int i = 0; i < niter - 1; ++i) {
    asm volatile("s_waitcnt vmcnt(%0)\n\ts_barrier" :: "i"(NL) : "memory");
    if (i + 2 < niter) {
      int nb = buf + 2; if (nb >= 3) nb -= 3;
      stage(i + 2, nb);
    }
    compute(buf);
    if (++buf == 3) buf = 0;
  }
  asm volatile("s_waitcnt vmcnt(0)\n\ts_barrier" ::: "memory");
  compute(buf);

  #pragma unroll
  for (int i = 0; i < 4; ++i) {
    #pragma unroll
    for (int r = 0; r < 4; ++r) {
      const int row = m0 + wm + i * 16 + qd * 4 + r;
      float rowf = 0.f;
      if (MODE == 2) rowf = rs[row] * scale;
      if (MODE == 3) rowf = 1.0f / rs[row];
      float rsum = 0.f;
      #pragma unroll
      for (int j = 0; j < 4; ++j) {
        const int col = n0 + wn + j * 16 + rl;
        float v = acc[i][j][r];
        if (MODE == 2) {
          const float s = v * rowf * cs[col];
          const unsigned short pb = f2b(__expf(s - scale));
          rsum += b2f(pb);
          ((unsigned short*)Cout)[(long long)bz * sC + (long long)row * ldc + col] = pb;
          continue;
        }
        if (MODE == 3) v *= rowf;
        const long long idx = (long long)bz * sC + (long long)row * ldc + col;
        if (OUT_BF16) ((unsigned short*)Cout)[idx] = f2b(v);
        else          ((float*)Cout)[idx] = v;
      }
      if (MODE == 2) {
        #pragma unroll
        for (int m = 1; m < 16; m <<= 1) rsum += __shfl_xor(rsum, m);
        if (rl == 0) atomicAdd(denom + row, rsum);
      }
    }
  }
}

// ---------------------------------------------------------------------------
// gemm256: 256x256/BK=64, 8 waves, 8-phase counted-vmcnt schedule (attn only;
// grid there is 512 blocks = 2 clean rounds). This round: sched_barrier(0)
// pinning after every wait (rule #18 — hipcc hoists register-only MFMA past
// inline-asm waitcnts), and deepened gate: A(kt+2)-top staged at ph4 so the
// ph4 gate is vmcnt(6) (3 half-tiles in flight, m201 depth).
// Stage schedule: ph1 A1t, ph2 A1b, ph3 B2t, ph4 B2b+A2t (VMC6),
//                 ph5 A2b, ph6 —, ph7 B3t, ph8 B3b (VMC4).
// Ledger: ph4 drains B1+A1 exactly (buf1 complete), leaves B2(4)+A2t(2)=6;
//         ph8 drains B2+A2 (buf0 complete), leaves B3=4. Overwrite safety:
//         A2t targets buf0-A whose last read is ph3 (barrier pair between).
// ---------------------------------------------------------------------------
template<bool OUT_BF16, int MODE>
__global__ __launch_bounds__(512, 2)
void gemm256(const unsigned short* __restrict__ A, const unsigned short* __restrict__ B,
             void* __restrict__ Cout, int K, int lda, int ldb, int ldc,
             long long sA, long long sB, long long sC,
             const float* __restrict__ rs, const float* __restrict__ cs,
             float* __restrict__ denom, int rcStride, float scale)
{
  extern __shared__ unsigned short S[];   // [2][A:16384 | B:16384] shorts

  const int bz = blockIdx.z;
  A += (long long)bz * sA;
  B += (long long)bz * sB;
  if (MODE == 2) { rs += (long long)bz * rcStride; cs += (long long)bz * rcStride;
                   denom += (long long)bz * rcStride; }
  if (MODE == 3) { rs += (long long)bz * rcStride; }
  const int m0 = blockIdx.y * 256, n0 = blockIdx.x * 256;
  const int tid = threadIdx.x;
  const int w = tid >> 6, lane = tid & 63;
  const int rl = lane & 15, qd = lane >> 4;
  const int wm = (w >> 2) * 128, wn = (w & 3) * 64;

  const int lr = lane >> 3;
  const int lg = ((lane & 7) ^ lr) * 8;
  const unsigned short* gA = A + (long long)(m0 + w * 8 + lr) * lda + lg;
  const unsigned short* gB = B + (long long)(n0 + w * 8 + lr) * ldb + lg;

  const int g0 = (qd ^ (rl & 7)) * 8;
  const int g1 = ((4 + qd) ^ (rl & 7)) * 8;
  const int aBase = (wm + rl) * 64, bBase = (wn + rl) * 64;

  floatx4 acc[8][4];
  #pragma unroll
  for (int i = 0; i < 8; ++i)
    #pragma unroll
    for (int j = 0; j < 4; ++j) acc[i][j] = 0.0f;

  auto stA = [&](int buf, int h, int kt) {
    unsigned short* d = S + buf * 32768 + h * 8192 + w * 512;
    const unsigned short* s = gA + (long long)(h * 128) * lda + kt * 64;
    gld16(s, d);
    gld16(s + (long long)64 * lda, d + 4096);
  };
  auto stB = [&](int buf, int h, int kt) {
    unsigned short* d = S + buf * 32768 + 16384 + h * 8192 + w * 512;
    const unsigned short* s = gB + (long long)(h * 128) * ldb + kt * 64;
    gld16(s, d);
    gld16(s + (long long)64 * ldb, d + 4096);
  };

  short8 fa[4][2], fl[2][2], fr[2][2];
  auto rdA = [&](int buf, int ih) {
    const unsigned short* p = S + buf * 32768 + aBase + ih * 4096;
    #pragma unroll
    for (int i = 0; i < 4; ++i) {
      fa[i][0] = *(const short8*)(p + i * 1024 + g0);
      fa[i][1] = *(const short8*)(p + i * 1024 + g1);
    }
  };
  auto rdB = [&](short8 (&fb)[2][2], int buf, int jh) {
    const unsigned short* p = S + buf * 32768 + 16384 + bBase + jh * 2048;
    #pragma unroll
    for (int j = 0; j < 2; ++j) {
      fb[j][0] = *(const short8*)(p + j * 1024 + g0);
      fb[j][1] = *(const short8*)(p + j * 1024 + g1);
    }
  };
  auto mm = [&](short8 (&fb)[2][2], int ih, int jh) {
    #pragma unroll
    for (int i = 0; i < 4; ++i)
      #pragma unroll
      for (int j = 0; j < 2; ++j) {
        floatx4& a = acc[ih * 4 + i][jh * 2 + j];
        a = __builtin_amdgcn_mfma_f32_16x16x32_bf16(fa[i][0], fb[j][0], a, 0, 0, 0);
        a = __builtin_amdgcn_mfma_f32_16x16x32_bf16(fa[i][1], fb[j][1], a, 0, 0, 0);
      }
  };

  auto iter = [&](int kt, bool st2, bool st3, bool tail) {
    // ph1
    rdA(0, 0); rdB(fl, 0, 0);
    stA(1, 0, kt + 1);
    BAR(); LGKM0; SCHED0;
    __builtin_amdgcn_s_setprio(1); mm(fl, 0, 0); __builtin_amdgcn_s_setprio(0);
    BAR();
    // ph2
    rdB(fr, 0, 1);
    stA(1, 1, kt + 1);
    BAR(); LGKM0; SCHED0;
    __builtin_amdgcn_s_setprio(1); mm(fr, 0, 1); __builtin_amdgcn_s_setprio(0);
    BAR();
    // ph3
    rdA(0, 1);
    if (st2) stB(0, 0, kt + 2);
    BAR(); LGKM0; SCHED0;
    __builtin_amdgcn_s_setprio(1); mm(fl, 1, 0); __builtin_amdgcn_s_setprio(0);
    BAR();
    // ph4
    if (st2) { stB(0, 1, kt + 2); stA(0, 0, kt + 2); }
    if (tail) { VMC0; } else { VMC6; }
    BAR(); SCHED0;
    __builtin_amdgcn_s_setprio(1); mm(fr, 1, 1); __builtin_amdgcn_s_setprio(0);
    BAR();
    // ph5
    rdA(1, 0); rdB(fl, 1, 0);
    if (st2) stA(0, 1, kt + 2);
    BAR(); LGKM0; SCHED0;
    __builtin_amdgcn_s_setprio(1); mm(fl, 0, 0); __builtin_amdgcn_s_setprio(0);
    BAR();
    // ph6
    rdB(fr, 1, 1);
    BAR(); LGKM0; SCHED0;
    __builtin_amdgcn_s_setprio(1); mm(fr, 0, 1); __builtin_amdgcn_s_setprio(0);
    BAR();
    // ph7
    rdA(1, 1);
    if (st3) stB(1, 0, kt + 3);
    BAR(); LGKM0; SCHED0;
    __builtin_amdgcn_s_setprio(1); mm(fl, 1, 0); __builtin_amdgcn_s_setprio(0);
    BAR();
    // ph8
    if (st3) stB(1, 1, kt + 3);
    if (!tail) { VMC4; }
    BAR(); SCHED0;
    __builtin_amdgcn_s_setprio(1); mm(fr, 1, 1); __builtin_amdgcn_s_setprio(0);
    BAR();
  };

  const int niter = K >> 7;   // K / 128; 2 K-tiles per iteration
  stB(0, 0, 0); stB(0, 1, 0); stA(0, 0, 0); stA(0, 1, 0);
  stB(1, 0, 1); stB(1, 1, 1);
  VMC4; BAR();
  for (int i = 0; i < niter - 1; ++i) iter(2 * i, true, true, false);
  iter(2 * (niter - 1), false, false, true);

  float cf4[4];
  if (MODE == 2) {
    #pragma unroll
    for (int j = 0; j < 4; ++j) cf4[j] = cs[n0 + wn + j * 16 + rl];
  }
  #pragma unroll
  for (int i = 0; i < 8; ++i) {
    #pragma unroll
    for (int r = 0; r < 4; ++r) {
      const int row = m0 + wm + i * 16 + qd * 4 + r;
      float rowf = 0.f;
      if (MODE == 2) rowf = rs[row] * scale;
      if (MODE == 3) rowf = 1.0f / rs[row];
      float rsum = 0.f;
      #pragma unroll
      for (int j = 0; j < 4; ++j) {
        const int col = n0 + wn + j * 16 + rl;
        float v = acc[i][j][r];
        if (MODE == 2) {
          const float s = v * rowf * cf4[j];
          const unsigned short pb = f2b(__expf(s - scale));
          rsum += b2f(pb);
          ((unsigned short*)Cout)[(long long)bz * sC + (long long)row * ldc + col] = pb;
          continue;
        }
        if (MODE == 3) v *= rowf;
        const long long idx = (long long)bz * sC + (long long)row * ldc + col;
        if (OUT_BF16) ((unsigned short*)Cout)[idx] = f2b(v);
        else          ((float*)Cout)[idx] = v;
      }
      if (MODE == 2) {
        #pragma unroll
        for (int m = 1; m < 16; m <<= 1) rsum += __shfl_xor(rsum, m);
        if (rl == 0) atomicAdd(denom + row, rsum);
      }
    }
  }
}

__global__ __launch_bounds__(256)
void zero_f(float* __restrict__ p, int n)
{
  const int i = blockIdx.x * 256 + threadIdx.x;
  if (i < n) p[i] = 0.f;
}

__global__ __launch_bounds__(256)
void conv_xT(const float* __restrict__ x, unsigned short* __restrict__ xT)
{
  const int b = blockIdx.z, t0 = blockIdx.x * 32, c0 = blockIdx.y * 32;
  const int tx = threadIdx.x & 31, ty = threadIdx.x >> 5;
  __shared__ float tile[32][33];
  const float* src = x + (long long)b * C_ * T_;
  #pragma unroll
  for (int r = 0; r < 4; ++r)
    tile[ty + 8 * r][tx] = src[(long long)(c0 + ty + 8 * r) * T_ + t0 + tx];
  __syncthreads();
  unsigned short* dst = xT + (long long)b * T_ * C_;
  #pragma unroll
  for (int r = 0; r < 4; ++r)
    dst[(long long)(t0 + ty + 8 * r) * C_ + c0 + tx] = f2b(tile[tx][ty + 8 * r]);
}

__global__ __launch_bounds__(256)
void conv_bf(const float* __restrict__ in, unsigned short* __restrict__ out, int n)
{
  const int i = blockIdx.x * 256 + threadIdx.x;
  if (i < n) out[i] = f2b(in[i]);
}

__global__ __launch_bounds__(256)
void dw_v(const unsigned short* __restrict__ qkv, const float* __restrict__ wdw,
          unsigned short* __restrict__ vout)
{
  const long long idx = (long long)blockIdx.x * 256 + threadIdx.x;
  const int t = (int)(idx % T_);
  const long long rem = idx / T_;
  const int c = (int)(rem % C_), b = (int)(rem / C_);
  const unsigned short* src = qkv + ((long long)(b * C3_ + 2 * C_ + c)) * T_;
  const float* wp = wdw + (2 * C_ + c) * 3;
  const float xm = (t > 0)      ? b2f(src[t - 1]) : 0.f;
  const float x0 = b2f(src[t]);
  const float xp = (t < T_ - 1) ? b2f(src[t + 1]) : 0.f;
  vout[(long long)(b * C_ + c) * T_ + t] = f2b(fmaf(wp[0], xm, fmaf(wp[1], x0, wp[2] * xp)));
}

__global__ __launch_bounds__(256)
void dw_qk_t(const unsigned short* __restrict__ qkv, const float* __restrict__ wdw,
             unsigned short* __restrict__ qT, unsigned short* __restrict__ kT)
{
  const int bz = blockIdx.z, b = bz >> 1, p = bz & 1;
  const int t0 = blockIdx.x * 32, c0 = blockIdx.y * 32;
  const int tx = threadIdx.x & 31, ty = threadIdx.x >> 5;
  __shared__ float tin[32][34];
  __shared__ float tout[32][33];
  const int chb = b * C3_ + p * C_;
  #pragma unroll
  for (int r = 0; r < 4; ++r) {
    const int cy = ty + 8 * r;
    const unsigned short* src = qkv + (long long)(chb + c0 + cy) * T_;
    int t = t0 - 1 + tx;
    tin[cy][tx] = (t >= 0 && t < T_) ? b2f(src[t]) : 0.f;
    if (tx < 2) {
      const int t2 = t0 + 31 + tx;
      tin[cy][32 + tx] = (t2 < T_) ? b2f(src[t2]) : 0.f;
    }
  }
  __syncthreads();
  #pragma unroll
  for (int r = 0; r < 4; ++r) {
    const int cy = ty + 8 * r;
    const float* wp = wdw + (long long)(p * C_ + c0 + cy) * 3;
    tout[tx][cy] = fmaf(wp[0], tin[cy][tx], fmaf(wp[1], tin[cy][tx + 1], wp[2] * tin[cy][tx + 2]));
  }
  __syncthreads();
  unsigned short* dst = (p == 0 ? qT : kT) + (long long)b * T_ * C_;
  #pragma unroll
  for (int r = 0; r < 4; ++r)
    dst[(long long)(t0 + ty + 8 * r) * C_ + c0 + tx] = f2b(tout[ty + 8 * r][tx]);
}

__global__ __launch_bounds__(256)
void norms_k(const unsigned short* __restrict__ qT, const unsigned short* __restrict__ kT,
             float* __restrict__ inv_nq, float* __restrict__ inv_nk)
{
  const int wave = threadIdx.x >> 6, lane = threadIdx.x & 63;
  const long long row = (long long)blockIdx.x * 4 + wave;
  const unsigned short* src = (blockIdx.y == 0 ? qT : kT) + row * C_ + lane * 8;
  const uint4 u = *(const uint4*)src;
  float ss = 0.f;
  const unsigned int uu[4] = {u.x, u.y, u.z, u.w};
  #pragma unroll
  for (int i = 0; i < 4; ++i) {
    const float lo = b2f(uu[i] & 0xFFFF), hi = b2f(uu[i] >> 16);
    ss = fmaf(lo, lo, ss); ss = fmaf(hi, hi, ss);
  }
  #pragma unroll
  for (int m = 32; m; m >>= 1) ss += __shfl_xor(ss, m);
  if (lane == 0)
    (blockIdx.y == 0 ? inv_nq : inv_nk)[row] = 1.f / fmaxf(sqrtf(ss), 1e-12f);
}

// ---------------------------------------------------------------------------
// Workspace arena (bytes), ~185.3 MB — same layout as round 0.
// ---------------------------------------------------------------------------
extern "C" void kernel_launch(void* const* d_in, const int* in_sizes, int n_in,
                              void* d_out, int out_size, void* d_ws, size_t ws_size,
                              hipStream_t stream)
{
  const float* x      = (const float*)d_in[0];
  const float* w_qkv  = (const float*)d_in[1];
  const float* w_dw   = (const float*)d_in[2];
  const float* w_proj = (const float*)d_in[3];
  float* out = (float*)d_out;

  static int attr_done = 0;
  if (!attr_done) {
    hipFuncSetAttribute((const void*)&gemm256<true, 2>,
                        hipFuncAttributeMaxDynamicSharedMemorySize, 131072);
    attr_done = 1;
  }

  char* base = (char*)d_ws;
  unsigned short* xT      = (unsigned short*)base;                    // early
  unsigned short* wqkv_bf = (unsigned short*)(base + 16777216);       // early
  unsigned short* av_t    = (unsigned short*)base;                    // late
  char* p = base + 67108864;
  unsigned short* qT = (unsigned short*)p; p += 16777216;
  unsigned short* kT = (unsigned short*)p; p += 16777216;
  unsigned short* vb = (unsigned short*)p; p += 16777216;
  unsigned short* attn   = (unsigned short*)p;
  unsigned short* qkv_bf = (unsigned short*)p;                        // early alias
  p += 67108864;
  unsigned short* wproj_bf = (unsigned short*)p; p += 524288;
  float* inv_nq = (float*)p; p += 65536;
  float* inv_nk = (float*)p; p += 65536;
  float* denom  = (float*)p;

  const long long TC = (long long)T_ * C_, TT = (long long)T_ * T_;

  // 0) conversions + denom zero
  conv_xT<<<dim3(T_ / 32, C_ / 32, B_), 256, 0, stream>>>(x, xT);
  conv_bf<<<(C3_ * C_) / 256, 256, 0, stream>>>(w_qkv, wqkv_bf, C3_ * C_);
  conv_bf<<<(C_ * C_) / 256, 256, 0, stream>>>(w_proj, wproj_bf, C_ * C_);
  zero_f<<<(B_ * T_) / 256, 256, 0, stream>>>(denom, B_ * T_);

  // 1) qkv: 128^2 kernel, grid 1536 blocks (full GPU)
  gemm_tn<true, 0><<<dim3(16, 12, B_), 256, 0, stream>>>(
      wqkv_bf, xT, qkv_bf, C_, C_, C_, T_,
      0LL, TC, (long long)C3_ * T_, nullptr, nullptr, nullptr, 0, 1.f);

  // 2) depthwise conv
  dw_v<<<(int)(((long long)B_ * C_ * T_) / 256), 256, 0, stream>>>(qkv_bf, w_dw, vb);
  dw_qk_t<<<dim3(T_ / 32, C_ / 32, B_ * 2), 256, 0, stream>>>(qkv_bf, w_dw, qT, kT);

  // 3) channel-L2 stats
  norms_k<<<dim3((B_ * T_) / 4, 2), 256, 0, stream>>>(qT, kT, inv_nq, inv_nk);

  // 4) attn: 256^2 8-phase kernel, grid 512 = 2 clean rounds
  gemm256<true, 2><<<dim3(8, 8, B_), 512, 131072, stream>>>(
      qT, kT, attn, C_, C_, C_, T_,
      TC, TC, TT, inv_nq, inv_nk, denom, T_, INV_TEMP);

  // 5) AV: 128^2 kernel, grid 512 blocks (full GPU)
  gemm_tn<true, 3><<<dim3(4, 16, B_), 256, 0, stream>>>(
      attn, vb, av_t, T_, T_, T_, C_,
      TT, (long long)C_ * T_, TC, denom, nullptr, nullptr, T_, 1.f);

  // 6) proj: 128^2 kernel, grid 512 blocks
  gemm_tn<false, 0><<<dim3(16, 4, B_), 256, 0, stream>>>(
      wproj_bf, av_t, out, C_, C_, C_, T_,
      0LL, TC, (long long)C_ * T_, nullptr, nullptr, nullptr, 0, 1.f);
}

// Round 4
// 319.722 us; speedup vs baseline: 1.0664x; 1.0332x over previous
//
#include <hip/hip_runtime.h>
#include <math.h>

static constexpr int B_ = 8, C_ = 512, T_ = 2048, C3_ = 1536;
static constexpr float INV_TEMP = 1.0f / 0.07f;

typedef __attribute__((ext_vector_type(8))) short short8;
typedef __attribute__((ext_vector_type(4))) float floatx4;

__device__ __forceinline__ float b2f(unsigned short u) {
  union { unsigned int i; float f; } v; v.i = ((unsigned int)u) << 16; return v.f;
}
__device__ __forceinline__ unsigned short f2b(float f) {
  union { float f; unsigned int i; } v; v.f = f;
  const unsigned int x = v.i;
  return (unsigned short)((x + 0x7FFFu + ((x >> 16) & 1u)) >> 16);
}
__device__ __forceinline__ void gld16(const unsigned short* g, unsigned short* l) {
  __builtin_amdgcn_global_load_lds(
      (const __attribute__((address_space(1))) void*)g,
      (__attribute__((address_space(3))) void*)l, 16, 0, 0);
}

#define FENCE  asm volatile("" ::: "memory")
#define BAR()  do { FENCE; __builtin_amdgcn_s_barrier(); FENCE; } while (0)
#define LGKM0  asm volatile("s_waitcnt lgkmcnt(0)" ::: "memory")
#define VMC4   asm volatile("s_waitcnt vmcnt(4)" ::: "memory")
#define VMC0   asm volatile("s_waitcnt vmcnt(0)" ::: "memory")

// ---------------------------------------------------------------------------
// gemm_tn: proven 128x128/BK=32 TN bf16 GEMM (3-deep LDS ring, counted
// vmcnt(4) at the barrier). Used for qkv / AV / proj where grid fit matters
// more than per-block pipeline depth.
// MODE 0: plain store. MODE 2: softmax epilogue. MODE 3: row divide.
// ---------------------------------------------------------------------------
template<bool OUT_BF16, int MODE>
__global__ __launch_bounds__(256)
void gemm_tn(const unsigned short* __restrict__ A, const unsigned short* __restrict__ B,
             void* __restrict__ Cout, int K, int lda, int ldb, int ldc,
             long long sA, long long sB, long long sC,
             const float* __restrict__ rs, const float* __restrict__ cs,
             float* __restrict__ denom, int rcStride, float scale)
{
  constexpr int NL = 4;   // gld16 per wave per tile

  const int bz = blockIdx.z;
  A += (long long)bz * sA;
  B += (long long)bz * sB;
  if (MODE == 2) { rs += (long long)bz * rcStride; cs += (long long)bz * rcStride;
                   denom += (long long)bz * rcStride; }
  if (MODE == 3) { rs += (long long)bz * rcStride; }
  const int m0 = blockIdx.y * 128, n0 = blockIdx.x * 128;
  const int tid = threadIdx.x;
  const int w = tid >> 6, lane = tid & 63;
  const int wm = (w >> 1) * 64, wn = (w & 1) * 64;
  const int rl = lane & 15, qd = lane >> 4;

  __shared__ __align__(16) unsigned short As[3][128 * 32];
  __shared__ __align__(16) unsigned short Bs[3][128 * 32];

  const int sr = lane >> 2, sg = lane & 3;
  const int ml0 = 32 * w + sr, ml1 = ml0 + 16;
  const int q0 = sg ^ ((ml0 >> 1) & 3), q1 = sg ^ ((ml1 >> 1) & 3);
  const unsigned short* gA0 = A + (long long)(m0 + ml0) * lda + q0 * 8;
  const unsigned short* gA1 = A + (long long)(m0 + ml1) * lda + q1 * 8;
  const unsigned short* gB0 = B + (long long)(n0 + ml0) * ldb + q0 * 8;
  const unsigned short* gB1 = B + (long long)(n0 + ml1) * ldb + q1 * 8;

  int aoff[4], boff[4];
  #pragma unroll
  for (int i = 0; i < 4; ++i) {
    const int mr = wm + i * 16 + rl;
    aoff[i] = mr * 32 + ((qd ^ ((mr >> 1) & 3)) * 8);
    const int nr = wn + i * 16 + rl;
    boff[i] = nr * 32 + ((qd ^ ((nr >> 1) & 3)) * 8);
  }

  floatx4 acc[4][4];
  #pragma unroll
  for (int i = 0; i < 4; ++i)
    #pragma unroll
    for (int j = 0; j < 4; ++j) acc[i][j] = 0.0f;

  auto stage = [&](int t, int bf) {
    const int ko = t * 32;
    gld16(gA0 + ko, As[bf] + (32 * w) * 32);
    gld16(gA1 + ko, As[bf] + (32 * w + 16) * 32);
    gld16(gB0 + ko, Bs[bf] + (32 * w) * 32);
    gld16(gB1 + ko, Bs[bf] + (32 * w + 16) * 32);
  };
  auto compute = [&](int bf) {
    short8 fa[4], fb[4];
    #pragma unroll
    for (int i = 0; i < 4; ++i) fa[i] = *(const short8*)(As[bf] + aoff[i]);
    #pragma unroll
    for (int j = 0; j < 4; ++j) fb[j] = *(const short8*)(Bs[bf] + boff[j]);
    #pragma unroll
    for (int i = 0; i < 4; ++i)
      #pragma unroll
      for (int j = 0; j < 4; ++j)
        acc[i][j] = __builtin_amdgcn_mfma_f32_16x16x32_bf16(fa[i], fb[j], acc[i][j], 0, 0, 0);
  };

  const int niter = K >> 5;
  stage(0, 0);
  stage(1, 1);
  int buf = 0;
  for (int i = 0; i < niter - 1; ++i) {
    asm volatile("s_waitcnt vmcnt(%0)\n\ts_barrier" :: "i"(NL) : "memory");
    if (i + 2 < niter) {
      int nb = buf + 2; if (nb >= 3) nb -= 3;
      stage(i + 2, nb);
    }
    compute(buf);
    if (++buf == 3) buf = 0;
  }
  asm volatile("s_waitcnt vmcnt(0)\n\ts_barrier" ::: "memory");
  compute(buf);

  #pragma unroll
  for (int i = 0; i < 4; ++i) {
    #pragma unroll
    for (int r = 0; r < 4; ++r) {
      const int row = m0 + wm + i * 16 + qd * 4 + r;
      float rowf = 0.f;
      if (MODE == 2) rowf = rs[row] * scale;
      if (MODE == 3) rowf = 1.0f / rs[row];
      float rsum = 0.f;
      #pragma unroll
      for (int j = 0; j < 4; ++j) {
        const int col = n0 + wn + j * 16 + rl;
        float v = acc[i][j][r];
        if (MODE == 2) {
          const float s = v * rowf * cs[col];
          const unsigned short pb = f2b(__expf(s - scale));
          rsum += b2f(pb);
          ((unsigned short*)Cout)[(long long)bz * sC + (long long)row * ldc + col] = pb;
          continue;
        }
        if (MODE == 3) v *= rowf;
        const long long idx = (long long)bz * sC + (long long)row * ldc + col;
        if (OUT_BF16) ((unsigned short*)Cout)[idx] = f2b(v);
        else          ((float*)Cout)[idx] = v;
      }
      if (MODE == 2) {
        #pragma unroll
        for (int m = 1; m < 16; m <<= 1) rsum += __shfl_xor(rsum, m);
        if (rl == 0) atomicAdd(denom + row, rsum);
      }
    }
  }
}

// ---------------------------------------------------------------------------
// gemm256: 256x256/BK=64, 8 waves, 8-phase counted-vmcnt schedule (attn only;
// grid there is 512 blocks = 2 clean rounds). ROUND-2 SCHEDULE RESTORED
// (measured 73.2 µs): no sched_barrier pinning (m141/round-3: -36%), vmcnt(4)
// gates at ph4/ph8.
// Stage schedule: ph1 A1t, ph2 A1b, ph3 B2t, ph4 B2b (VMC4),
//                 ph5 A2t, ph6 A2b, ph7 B3t, ph8 B3b (VMC4).
// Ledger: ph4 drains B1+A1 (buf1 complete), leaves B2=4 in flight;
//         ph8 drains B2+A2 (buf0 complete), leaves B3=4. Overwrite safety:
//         every stage dest slot was last read >=1 barrier pair earlier.
// ---------------------------------------------------------------------------
template<bool OUT_BF16, int MODE>
__global__ __launch_bounds__(512, 2)
void gemm256(const unsigned short* __restrict__ A, const unsigned short* __restrict__ B,
             void* __restrict__ Cout, int K, int lda, int ldb, int ldc,
             long long sA, long long sB, long long sC,
             const float* __restrict__ rs, const float* __restrict__ cs,
             float* __restrict__ denom, int rcStride, float scale)
{
  extern __shared__ unsigned short S[];   // [2][A:16384 | B:16384] shorts

  const int bz = blockIdx.z;
  A += (long long)bz * sA;
  B += (long long)bz * sB;
  if (MODE == 2) { rs += (long long)bz * rcStride; cs += (long long)bz * rcStride;
                   denom += (long long)bz * rcStride; }
  if (MODE == 3) { rs += (long long)bz * rcStride; }
  const int m0 = blockIdx.y * 256, n0 = blockIdx.x * 256;
  const int tid = threadIdx.x;
  const int w = tid >> 6, lane = tid & 63;
  const int rl = lane & 15, qd = lane >> 4;
  const int wm = (w >> 2) * 128, wn = (w & 3) * 64;

  const int lr = lane >> 3;
  const int lg = ((lane & 7) ^ lr) * 8;
  const unsigned short* gA = A + (long long)(m0 + w * 8 + lr) * lda + lg;
  const unsigned short* gB = B + (long long)(n0 + w * 8 + lr) * ldb + lg;

  const int g0 = (qd ^ (rl & 7)) * 8;
  const int g1 = ((4 + qd) ^ (rl & 7)) * 8;
  const int aBase = (wm + rl) * 64, bBase = (wn + rl) * 64;

  floatx4 acc[8][4];
  #pragma unroll
  for (int i = 0; i < 8; ++i)
    #pragma unroll
    for (int j = 0; j < 4; ++j) acc[i][j] = 0.0f;

  auto stA = [&](int buf, int h, int kt) {
    unsigned short* d = S + buf * 32768 + h * 8192 + w * 512;
    const unsigned short* s = gA + (long long)(h * 128) * lda + kt * 64;
    gld16(s, d);
    gld16(s + (long long)64 * lda, d + 4096);
  };
  auto stB = [&](int buf, int h, int kt) {
    unsigned short* d = S + buf * 32768 + 16384 + h * 8192 + w * 512;
    const unsigned short* s = gB + (long long)(h * 128) * ldb + kt * 64;
    gld16(s, d);
    gld16(s + (long long)64 * ldb, d + 4096);
  };

  short8 fa[4][2], fl[2][2], fr[2][2];
  auto rdA = [&](int buf, int ih) {
    const unsigned short* p = S + buf * 32768 + aBase + ih * 4096;
    #pragma unroll
    for (int i = 0; i < 4; ++i) {
      fa[i][0] = *(const short8*)(p + i * 1024 + g0);
      fa[i][1] = *(const short8*)(p + i * 1024 + g1);
    }
  };
  auto rdB = [&](short8 (&fb)[2][2], int buf, int jh) {
    const unsigned short* p = S + buf * 32768 + 16384 + bBase + jh * 2048;
    #pragma unroll
    for (int j = 0; j < 2; ++j) {
      fb[j][0] = *(const short8*)(p + j * 1024 + g0);
      fb[j][1] = *(const short8*)(p + j * 1024 + g1);
    }
  };
  auto mm = [&](short8 (&fb)[2][2], int ih, int jh) {
    #pragma unroll
    for (int i = 0; i < 4; ++i)
      #pragma unroll
      for (int j = 0; j < 2; ++j) {
        floatx4& a = acc[ih * 4 + i][jh * 2 + j];
        a = __builtin_amdgcn_mfma_f32_16x16x32_bf16(fa[i][0], fb[j][0], a, 0, 0, 0);
        a = __builtin_amdgcn_mfma_f32_16x16x32_bf16(fa[i][1], fb[j][1], a, 0, 0, 0);
      }
  };

  auto iter = [&](int kt, bool st2, bool st3, bool tail) {
    // ph1
    rdA(0, 0); rdB(fl, 0, 0);
    stA(1, 0, kt + 1);
    BAR(); LGKM0;
    __builtin_amdgcn_s_setprio(1); mm(fl, 0, 0); __builtin_amdgcn_s_setprio(0);
    BAR();
    // ph2
    rdB(fr, 0, 1);
    stA(1, 1, kt + 1);
    BAR(); LGKM0;
    __builtin_amdgcn_s_setprio(1); mm(fr, 0, 1); __builtin_amdgcn_s_setprio(0);
    BAR();
    // ph3
    rdA(0, 1);
    if (st2) stB(0, 0, kt + 2);
    BAR(); LGKM0;
    __builtin_amdgcn_s_setprio(1); mm(fl, 1, 0); __builtin_amdgcn_s_setprio(0);
    BAR();
    // ph4
    if (st2) stB(0, 1, kt + 2);
    if (tail) { VMC0; } else { VMC4; }
    BAR();
    __builtin_amdgcn_s_setprio(1); mm(fr, 1, 1); __builtin_amdgcn_s_setprio(0);
    BAR();
    // ph5
    rdA(1, 0); rdB(fl, 1, 0);
    if (st2) stA(0, 0, kt + 2);
    BAR(); LGKM0;
    __builtin_amdgcn_s_setprio(1); mm(fl, 0, 0); __builtin_amdgcn_s_setprio(0);
    BAR();
    // ph6
    rdB(fr, 1, 1);
    if (st2) stA(0, 1, kt + 2);
    BAR(); LGKM0;
    __builtin_amdgcn_s_setprio(1); mm(fr, 0, 1); __builtin_amdgcn_s_setprio(0);
    BAR();
    // ph7
    rdA(1, 1);
    if (st3) stB(1, 0, kt + 3);
    BAR(); LGKM0;
    __builtin_amdgcn_s_setprio(1); mm(fl, 1, 0); __builtin_amdgcn_s_setprio(0);
    BAR();
    // ph8
    if (st3) stB(1, 1, kt + 3);
    if (!tail) { VMC4; }
    BAR();
    __builtin_amdgcn_s_setprio(1); mm(fr, 1, 1); __builtin_amdgcn_s_setprio(0);
    BAR();
  };

  const int niter = K >> 7;   // K / 128; 2 K-tiles per iteration
  stB(0, 0, 0); stB(0, 1, 0); stA(0, 0, 0); stA(0, 1, 0);
  stB(1, 0, 1); stB(1, 1, 1);
  VMC4; BAR();
  for (int i = 0; i < niter - 1; ++i) iter(2 * i, true, true, false);
  iter(2 * (niter - 1), false, false, true);

  float cf4[4];
  if (MODE == 2) {
    #pragma unroll
    for (int j = 0; j < 4; ++j) cf4[j] = cs[n0 + wn + j * 16 + rl];
  }
  #pragma unroll
  for (int i = 0; i < 8; ++i) {
    #pragma unroll
    for (int r = 0; r < 4; ++r) {
      const int row = m0 + wm + i * 16 + qd * 4 + r;
      float rowf = 0.f;
      if (MODE == 2) rowf = rs[row] * scale;
      if (MODE == 3) rowf = 1.0f / rs[row];
      float rsum = 0.f;
      #pragma unroll
      for (int j = 0; j < 4; ++j) {
        const int col = n0 + wn + j * 16 + rl;
        float v = acc[i][j][r];
        if (MODE == 2) {
          const float s = v * rowf * cf4[j];
          const unsigned short pb = f2b(__expf(s - scale));
          rsum += b2f(pb);
          ((unsigned short*)Cout)[(long long)bz * sC + (long long)row * ldc + col] = pb;
          continue;
        }
        if (MODE == 3) v *= rowf;
        const long long idx = (long long)bz * sC + (long long)row * ldc + col;
        if (OUT_BF16) ((unsigned short*)Cout)[idx] = f2b(v);
        else          ((float*)Cout)[idx] = v;
      }
      if (MODE == 2) {
        #pragma unroll
        for (int m = 1; m < 16; m <<= 1) rsum += __shfl_xor(rsum, m);
        if (rl == 0) atomicAdd(denom + row, rsum);
      }
    }
  }
}

__global__ __launch_bounds__(256)
void zero_f(float* __restrict__ p, int n)
{
  const int i = blockIdx.x * 256 + threadIdx.x;
  if (i < n) p[i] = 0.f;
}

__global__ __launch_bounds__(256)
void conv_xT(const float* __restrict__ x, unsigned short* __restrict__ xT)
{
  const int b = blockIdx.z, t0 = blockIdx.x * 32, c0 = blockIdx.y * 32;
  const int tx = threadIdx.x & 31, ty = threadIdx.x >> 5;
  __shared__ float tile[32][33];
  const float* src = x + (long long)b * C_ * T_;
  #pragma unroll
  for (int r = 0; r < 4; ++r)
    tile[ty + 8 * r][tx] = src[(long long)(c0 + ty + 8 * r) * T_ + t0 + tx];
  __syncthreads();
  unsigned short* dst = xT + (long long)b * T_ * C_;
  #pragma unroll
  for (int r = 0; r < 4; ++r)
    dst[(long long)(t0 + ty + 8 * r) * C_ + c0 + tx] = f2b(tile[tx][ty + 8 * r]);
}

__global__ __launch_bounds__(256)
void conv_bf(const float* __restrict__ in, unsigned short* __restrict__ out, int n)
{
  const int i = blockIdx.x * 256 + threadIdx.x;
  if (i < n) out[i] = f2b(in[i]);
}

// ---------------------------------------------------------------------------
// Depthwise-3 (zero pad) on v channels, VECTORIZED: each thread computes 8
// contiguous t via one short8 load + 2 edge scalars. A 256-thread block
// covers exactly one (b,c) row (T/8 = 256 segments), so the 3 dw weights are
// wave-uniform broadcasts. bf16 in [B,3C,T] -> v [B,C,T]
// ---------------------------------------------------------------------------
__global__ __launch_bounds__(256)
void dw_v(const unsigned short* __restrict__ qkv, const float* __restrict__ wdw,
          unsigned short* __restrict__ vout)
{
  const long long seg = (long long)blockIdx.x * 256 + threadIdx.x;  // [B*C*T/8)
  const int tseg = (int)(seg % (T_ / 8));
  const long long rem = seg / (T_ / 8);
  const int c = (int)(rem % C_), b = (int)(rem / C_);
  const int t0 = tseg * 8;
  const unsigned short* src = qkv + ((long long)(b * C3_ + 2 * C_ + c)) * T_;
  const float* wp = wdw + (2 * C_ + c) * 3;
  const float w0 = wp[0], w1 = wp[1], w2 = wp[2];
  const short8 cur = *(const short8*)(src + t0);
  float xv[10];
  xv[0] = (t0 > 0) ? b2f(src[t0 - 1]) : 0.f;
  #pragma unroll
  for (int k = 0; k < 8; ++k) xv[k + 1] = b2f((unsigned short)cur[k]);
  xv[9] = (t0 + 8 < T_) ? b2f(src[t0 + 8]) : 0.f;
  short8 o;
  #pragma unroll
  for (int k = 0; k < 8; ++k)
    o[k] = (short)f2b(fmaf(w0, xv[k], fmaf(w1, xv[k + 1], w2 * xv[k + 2])));
  *(short8*)(vout + (long long)(b * C_ + c) * T_ + t0) = o;
}

__global__ __launch_bounds__(256)
void dw_qk_t(const unsigned short* __restrict__ qkv, const float* __restrict__ wdw,
             unsigned short* __restrict__ qT, unsigned short* __restrict__ kT)
{
  const int bz = blockIdx.z, b = bz >> 1, p = bz & 1;
  const int t0 = blockIdx.x * 32, c0 = blockIdx.y * 32;
  const int tx = threadIdx.x & 31, ty = threadIdx.x >> 5;
  __shared__ float tin[32][34];
  __shared__ float tout[32][33];
  const int chb = b * C3_ + p * C_;
  #pragma unroll
  for (int r = 0; r < 4; ++r) {
    const int cy = ty + 8 * r;
    const unsigned short* src = qkv + (long long)(chb + c0 + cy) * T_;
    int t = t0 - 1 + tx;
    tin[cy][tx] = (t >= 0 && t < T_) ? b2f(src[t]) : 0.f;
    if (tx < 2) {
      const int t2 = t0 + 31 + tx;
      tin[cy][32 + tx] = (t2 < T_) ? b2f(src[t2]) : 0.f;
    }
  }
  __syncthreads();
  #pragma unroll
  for (int r = 0; r < 4; ++r) {
    const int cy = ty + 8 * r;
    const float* wp = wdw + (long long)(p * C_ + c0 + cy) * 3;
    tout[tx][cy] = fmaf(wp[0], tin[cy][tx], fmaf(wp[1], tin[cy][tx + 1], wp[2] * tin[cy][tx + 2]));
  }
  __syncthreads();
  unsigned short* dst = (p == 0 ? qT : kT) + (long long)b * T_ * C_;
  #pragma unroll
  for (int r = 0; r < 4; ++r)
    dst[(long long)(t0 + ty + 8 * r) * C_ + c0 + tx] = f2b(tout[ty + 8 * r][tx]);
}

__global__ __launch_bounds__(256)
void norms_k(const unsigned short* __restrict__ qT, const unsigned short* __restrict__ kT,
             float* __restrict__ inv_nq, float* __restrict__ inv_nk)
{
  const int wave = threadIdx.x >> 6, lane = threadIdx.x & 63;
  const long long row = (long long)blockIdx.x * 4 + wave;
  const unsigned short* src = (blockIdx.y == 0 ? qT : kT) + row * C_ + lane * 8;
  const uint4 u = *(const uint4*)src;
  float ss = 0.f;
  const unsigned int uu[4] = {u.x, u.y, u.z, u.w};
  #pragma unroll
  for (int i = 0; i < 4; ++i) {
    const float lo = b2f(uu[i] & 0xFFFF), hi = b2f(uu[i] >> 16);
    ss = fmaf(lo, lo, ss); ss = fmaf(hi, hi, ss);
  }
  #pragma unroll
  for (int m = 32; m; m >>= 1) ss += __shfl_xor(ss, m);
  if (lane == 0)
    (blockIdx.y == 0 ? inv_nq : inv_nk)[row] = 1.f / fmaxf(sqrtf(ss), 1e-12f);
}

// ---------------------------------------------------------------------------
// Workspace arena (bytes), ~185.3 MB — same layout as round 0.
// ---------------------------------------------------------------------------
extern "C" void kernel_launch(void* const* d_in, const int* in_sizes, int n_in,
                              void* d_out, int out_size, void* d_ws, size_t ws_size,
                              hipStream_t stream)
{
  const float* x      = (const float*)d_in[0];
  const float* w_qkv  = (const float*)d_in[1];
  const float* w_dw   = (const float*)d_in[2];
  const float* w_proj = (const float*)d_in[3];
  float* out = (float*)d_out;

  static int attr_done = 0;
  if (!attr_done) {
    hipFuncSetAttribute((const void*)&gemm256<true, 2>,
                        hipFuncAttributeMaxDynamicSharedMemorySize, 131072);
    attr_done = 1;
  }

  char* base = (char*)d_ws;
  unsigned short* xT      = (unsigned short*)base;                    // early
  unsigned short* wqkv_bf = (unsigned short*)(base + 16777216);       // early
  unsigned short* av_t    = (unsigned short*)base;                    // late
  char* p = base + 67108864;
  unsigned short* qT = (unsigned short*)p; p += 16777216;
  unsigned short* kT = (unsigned short*)p; p += 16777216;
  unsigned short* vb = (unsigned short*)p; p += 16777216;
  unsigned short* attn   = (unsigned short*)p;
  unsigned short* qkv_bf = (unsigned short*)p;                        // early alias
  p += 67108864;
  unsigned short* wproj_bf = (unsigned short*)p; p += 524288;
  float* inv_nq = (float*)p; p += 65536;
  float* inv_nk = (float*)p; p += 65536;
  float* denom  = (float*)p;

  const long long TC = (long long)T_ * C_, TT = (long long)T_ * T_;

  // 0) conversions + denom zero
  conv_xT<<<dim3(T_ / 32, C_ / 32, B_), 256, 0, stream>>>(x, xT);
  conv_bf<<<(C3_ * C_) / 256, 256, 0, stream>>>(w_qkv, wqkv_bf, C3_ * C_);
  conv_bf<<<(C_ * C_) / 256, 256, 0, stream>>>(w_proj, wproj_bf, C_ * C_);
  zero_f<<<(B_ * T_) / 256, 256, 0, stream>>>(denom, B_ * T_);

  // 1) qkv: 128^2 kernel, grid 1536 blocks (full GPU)
  gemm_tn<true, 0><<<dim3(16, 12, B_), 256, 0, stream>>>(
      wqkv_bf, xT, qkv_bf, C_, C_, C_, T_,
      0LL, TC, (long long)C3_ * T_, nullptr, nullptr, nullptr, 0, 1.f);

  // 2) depthwise conv (dw_v vectorized: 8 t per thread)
  dw_v<<<(int)(((long long)B_ * C_ * T_) / (256 * 8)), 256, 0, stream>>>(qkv_bf, w_dw, vb);
  dw_qk_t<<<dim3(T_ / 32, C_ / 32, B_ * 2), 256, 0, stream>>>(qkv_bf, w_dw, qT, kT);

  // 3) channel-L2 stats
  norms_k<<<dim3((B_ * T_) / 4, 2), 256, 0, stream>>>(qT, kT, inv_nq, inv_nk);

  // 4) attn: 256^2 8-phase kernel (round-2 schedule), grid 512 = 2 clean rounds
  gemm256<true, 2><<<dim3(8, 8, B_), 512, 131072, stream>>>(
      qT, kT, attn, C_, C_, C_, T_,
      TC, TC, TT, inv_nq, inv_nk, denom, T_, INV_TEMP);

  // 5) AV: 128^2 kernel, grid 512 blocks (full GPU)
  gemm_tn<true, 3><<<dim3(4, 16, B_), 256, 0, stream>>>(
      attn, vb, av_t, T_, T_, T_, C_,
      TT, (long long)C_ * T_, TC, denom, nullptr, nullptr, T_, 1.f);

  // 6) proj: 128^2 kernel, grid 512 blocks
  gemm_tn<false, 0><<<dim3(16, 4, B_), 256, 0, stream>>>(
      wproj_bf, av_t, out, C_, C_, C_, T_,
      0LL, TC, (long long)C_ * T_, nullptr, nullptr, nullptr, 0, 1.f);
}